// Round 1
// baseline (737.972 us; speedup 1.0000x reference)
//
#include <hip/hip_runtime.h>
#include <hip/hip_bf16.h>
#include <math.h>

typedef __hip_bfloat16 bf16;
#define DEV __device__ __forceinline__

constexpr int BATCH = 4;
constexpr int DIM   = 256;
constexpr int C2    = 128;
constexpr int GK    = 40;     // HEADS*KS = 8*5
constexpr int HH    = 128;
constexpr int WW    = 128;
constexpr int NPIX  = HH * WW;   // 16384
constexpr int TPB   = 256;

DEV float toF(float v) { return v; }
DEV float toF(bf16 v)  { return __bfloat162float(v); }
DEV void  stF(float* p, float v) { *p = v; }
DEV void  stF(bf16*  p, float v) { *p = __float2bfloat16(v); }

// -------------------- pointwise conv (1x1): out[b,o,p] = act(sum_c W[o,c]*in[b,c,p]+bias[o])
// grid: (NPIX/TPB, O/8, BATCH); block TPB. Weight/bias indices are block-uniform -> s_loads.
template<int C, int ACT, typename TIN, typename TOUT>
__global__ __launch_bounds__(TPB) void pw_kernel(
    const TIN* __restrict__ in, int in_cstride,
    const float* __restrict__ w, const float* __restrict__ bias,
    TOUT* __restrict__ out, int out_cstride) {
  const int p  = blockIdx.x * TPB + threadIdx.x;
  const int o0 = blockIdx.y * 8;
  const int b  = blockIdx.z;
  const TIN*   inb = in + ((size_t)b * in_cstride) * NPIX + p;
  const float* wr  = w + (size_t)o0 * C;
  float acc[8];
#pragma unroll
  for (int j = 0; j < 8; ++j) acc[j] = bias[o0 + j];
#pragma unroll 4
  for (int c = 0; c < C; ++c) {
    float xv = toF(inb[(size_t)c * NPIX]);
#pragma unroll
    for (int j = 0; j < 8; ++j) acc[j] = fmaf(xv, wr[j * C + c], acc[j]);
  }
  TOUT* ob = out + ((size_t)b * out_cstride + o0) * NPIX + p;
#pragma unroll
  for (int j = 0; j < 8; ++j) {
    float v = acc[j];
    if (ACT == 1) v = fmaxf(v, 0.0f);
    if (ACT == 2) v = tanhf(v);
    stF(ob + (size_t)j * NPIX, v);
  }
}

// -------------------- depthwise 1x7 conv along W, zero pad 3
template<typename TIN>
__global__ __launch_bounds__(TPB) void dwh_kernel(
    const TIN* __restrict__ in, int in_cstride,
    const float* __restrict__ w7, const float* __restrict__ bias,
    bf16* __restrict__ out) {
  const int idx = blockIdx.x * TPB + threadIdx.x;
  const int wp  = idx & (WW - 1);
  const int rest = idx / WW;
  const int hp  = rest & (HH - 1);
  const int bc  = rest / HH;
  const int c   = bc & (C2 - 1);
  const int b   = bc / C2;
  const TIN* xr = in + ((size_t)b * in_cstride + c) * NPIX + hp * WW;
  float acc = bias[c];
#pragma unroll
  for (int j = 0; j < 7; ++j) {
    int wq = wp - 3 + j;
    if (wq >= 0 && wq < WW) acc = fmaf(w7[c * 7 + j], toF(xr[wq]), acc);
  }
  out[(size_t)bc * NPIX + hp * WW + wp] = __float2bfloat16(acc);
}

// -------------------- depthwise 7x1 conv along H, zero pad 3
template<typename TIN>
__global__ __launch_bounds__(TPB) void dwv_kernel(
    const TIN* __restrict__ in, int in_cstride,
    const float* __restrict__ w7, const float* __restrict__ bias,
    bf16* __restrict__ out) {
  const int idx = blockIdx.x * TPB + threadIdx.x;
  const int wp  = idx & (WW - 1);
  const int rest = idx / WW;
  const int hp  = rest & (HH - 1);
  const int bc  = rest / HH;
  const int c   = bc & (C2 - 1);
  const int b   = bc / C2;
  const TIN* xcol = in + ((size_t)b * in_cstride + c) * NPIX + wp;
  float acc = bias[c];
#pragma unroll
  for (int j = 0; j < 7; ++j) {
    int hq = hp - 3 + j;
    if (hq >= 0 && hq < HH) acc = fmaf(w7[c * 7 + j], toF(xcol[(size_t)hq * WW]), acc);
  }
  out[(size_t)bc * NPIX + hp * WW + wp] = __float2bfloat16(acc);
}

// -------------------- FSA horizontal: taps [-3..3] along W, 5 taps, group kernels
// taps: (x[-3]+x[-2])/2, x[-1], x[0], x[+1], (x[+2]+x[+3])/2
template<typename TIN>
__global__ __launch_bounds__(TPB) void fsah_kernel(
    const TIN* __restrict__ x, int x_cstride,
    const bf16* __restrict__ kern, bf16* __restrict__ out) {
  const int idx = blockIdx.x * TPB + threadIdx.x;
  const int wp  = idx & (WW - 1);
  const int rest = idx / WW;
  const int hp  = rest & (HH - 1);
  const int bc  = rest / HH;
  const int c   = bc & (C2 - 1);
  const int b   = bc / C2;
  const TIN* xr = x + ((size_t)b * x_cstride + c) * NPIX + hp * WW;
  float xs[7];
#pragma unroll
  for (int j = 0; j < 7; ++j) {
    int wq = wp - 3 + j;
    xs[j] = (wq >= 0 && wq < WW) ? toF(xr[wq]) : 0.0f;
  }
  const bf16* kr = kern + ((size_t)b * GK + (c >> 4) * 5) * NPIX + hp * WW + wp;
  float acc = 0.5f * (xs[0] + xs[1]) * toF(kr[0]);
  acc = fmaf(xs[2], toF(kr[(size_t)1 * NPIX]), acc);
  acc = fmaf(xs[3], toF(kr[(size_t)2 * NPIX]), acc);
  acc = fmaf(xs[4], toF(kr[(size_t)3 * NPIX]), acc);
  acc = fmaf(0.5f * (xs[5] + xs[6]), toF(kr[(size_t)4 * NPIX]), acc);
  out[(size_t)bc * NPIX + hp * WW + wp] = __float2bfloat16(acc);
}

// -------------------- FSA vertical: taps along H
template<typename TIN>
__global__ __launch_bounds__(TPB) void fsav_kernel(
    const TIN* __restrict__ x, int x_cstride,
    const bf16* __restrict__ kern, bf16* __restrict__ out) {
  const int idx = blockIdx.x * TPB + threadIdx.x;
  const int wp  = idx & (WW - 1);
  const int rest = idx / WW;
  const int hp  = rest & (HH - 1);
  const int bc  = rest / HH;
  const int c   = bc & (C2 - 1);
  const int b   = bc / C2;
  const TIN* xcol = x + ((size_t)b * x_cstride + c) * NPIX + wp;
  float xs[7];
#pragma unroll
  for (int j = 0; j < 7; ++j) {
    int hq = hp - 3 + j;
    xs[j] = (hq >= 0 && hq < HH) ? toF(xcol[(size_t)hq * WW]) : 0.0f;
  }
  const bf16* kr = kern + ((size_t)b * GK + (c >> 4) * 5) * NPIX + hp * WW + wp;
  float acc = 0.5f * (xs[0] + xs[1]) * toF(kr[0]);
  acc = fmaf(xs[2], toF(kr[(size_t)1 * NPIX]), acc);
  acc = fmaf(xs[3], toF(kr[(size_t)2 * NPIX]), acc);
  acc = fmaf(xs[4], toF(kr[(size_t)3 * NPIX]), acc);
  acc = fmaf(0.5f * (xs[5] + xs[6]), toF(kr[(size_t)4 * NPIX]), acc);
  out[(size_t)bc * NPIX + hp * WW + wp] = __float2bfloat16(acc);
}

// -------------------- block reduction helper (result valid in thread 0)
DEV float block_reduce_sum(float v) {
#pragma unroll
  for (int off = 32; off > 0; off >>= 1) v += __shfl_down(v, off, 64);
  __shared__ float ls[TPB / 64];
  const int lane = threadIdx.x & 63;
  const int wid  = threadIdx.x >> 6;
  if (lane == 0) ls[wid] = v;
  __syncthreads();
  float s = 0.0f;
  if (threadIdx.x == 0) {
#pragma unroll
    for (int i = 0; i < TPB / 64; ++i) s += ls[i];
  }
  return s;
}

// at_mean[bc] = mean_n attn[bc,n]   grid: BATCH*C2
__global__ __launch_bounds__(TPB) void mean_n_kernel(const bf16* __restrict__ in,
                                                     float* __restrict__ out) {
  const int bc = blockIdx.x;
  const bf16* r = in + (size_t)bc * NPIX;
  float s = 0.0f;
  for (int i = threadIdx.x; i < NPIX; i += TPB) s += toF(r[i]);
  s = block_reduce_sum(s);
  if (threadIdx.x == 0) out[bc] = s * (1.0f / NPIX);
}

// xc_mean[b,n] = mean_c xc[b,c,n]   grid: (NPIX/TPB, BATCH)
__global__ __launch_bounds__(TPB) void xcmean_kernel(const bf16* __restrict__ xc,
                                                     float* __restrict__ out) {
  const int p = blockIdx.x * TPB + threadIdx.x;
  const int b = blockIdx.y;
  const bf16* r = xc + (size_t)b * C2 * NPIX + p;
  float s = 0.0f;
#pragma unroll 4
  for (int c = 0; c < C2; ++c) s += toF(r[(size_t)c * NPIX]);
  out[(size_t)b * NPIX + p] = s * (1.0f / C2);
}

// s_sig[b,n] = sigmoid( sum_c at_mean[b,c]*xc[b,c,n] / C2 )   grid: (NPIX/TPB, BATCH)
__global__ __launch_bounds__(TPB) void ssig_kernel(const bf16* __restrict__ xc,
                                                   const float* __restrict__ at_mean,
                                                   float* __restrict__ out) {
  __shared__ float am[C2];
  const int b = blockIdx.y;
  if (threadIdx.x < C2) am[threadIdx.x] = at_mean[b * C2 + threadIdx.x];
  __syncthreads();
  const int p = blockIdx.x * TPB + threadIdx.x;
  const bf16* r = xc + (size_t)b * C2 * NPIX + p;
  float s = 0.0f;
#pragma unroll 4
  for (int c = 0; c < C2; ++c) s = fmaf(am[c], toF(r[(size_t)c * NPIX]), s);
  out[(size_t)b * NPIX + p] = 1.0f / (1.0f + expf(-s * (1.0f / C2)));
}

// c_sig[b,c] = sigmoid( sum_n attn[b,c,n]*xc_mean[b,n] / NPIX )   grid: BATCH*C2
__global__ __launch_bounds__(TPB) void csig_kernel(const bf16* __restrict__ attn,
                                                   const float* __restrict__ xc_mean,
                                                   float* __restrict__ out) {
  const int bc = blockIdx.x;
  const int b  = bc / C2;
  const bf16* r = attn + (size_t)bc * NPIX;
  const float* m = xc_mean + (size_t)b * NPIX;
  float s = 0.0f;
  for (int i = threadIdx.x; i < NPIX; i += TPB) s = fmaf(toF(r[i]), m[i], s);
  s = block_reduce_sum(s);
  if (threadIdx.x == 0) out[bc] = 1.0f / (1.0f + expf(-s * (1.0f / NPIX)));
}

// cat[b,c,n]: c<128 -> s_sig[b,n]*xc[b,c,n] ; else c_sig[b,c-128]*attn[b,c-128,n]
// grid: (NPIX/TPB, DIM, BATCH)
__global__ __launch_bounds__(TPB) void concat_kernel(const bf16* __restrict__ xc,
                                                     const bf16* __restrict__ attn,
                                                     const float* __restrict__ s_sig,
                                                     const float* __restrict__ c_sig,
                                                     bf16* __restrict__ out) {
  const int p = blockIdx.x * TPB + threadIdx.x;
  const int c = blockIdx.y;
  const int b = blockIdx.z;
  float v;
  if (c < C2) {
    v = s_sig[(size_t)b * NPIX + p] * toF(xc[((size_t)b * C2 + c) * NPIX + p]);
  } else {
    v = c_sig[b * C2 + (c - C2)] * toF(attn[((size_t)b * C2 + (c - C2)) * NPIX + p]);
  }
  out[((size_t)b * DIM + c) * NPIX + p] = __float2bfloat16(v);
}

extern "C" void kernel_launch(void* const* d_in, const int* in_sizes, int n_in,
                              void* d_out, int out_size, void* d_ws, size_t ws_size,
                              hipStream_t stream) {
  const float* x    = (const float*)d_in[0];
  const float* piw  = (const float*)d_in[1];
  const float* pib  = (const float*)d_in[2];
  const float* hkdw = (const float*)d_in[3];
  const float* hkdb = (const float*)d_in[4];
  const float* hkpw = (const float*)d_in[5];
  const float* hkpb = (const float*)d_in[6];
  const float* vkdw = (const float*)d_in[7];
  const float* vkdb = (const float*)d_in[8];
  const float* vkpw = (const float*)d_in[9];
  const float* vkpb = (const float*)d_in[10];
  const float* cbw1 = (const float*)d_in[11];
  const float* cbb1 = (const float*)d_in[12];
  const float* cbw2 = (const float*)d_in[13];
  const float* cbb2 = (const float*)d_in[14];
  const float* pow_ = (const float*)d_in[15];
  const float* pob  = (const float*)d_in[16];
  float* out = (float*)d_out;

  char* ws = (char*)d_ws;
  size_t off = 0;
  auto alloc = [&](size_t bytes) -> char* {
    char* p = ws + off;
    off += (bytes + 255) & ~(size_t)255;
    return p;
  };
  float* h      = (float*)alloc((size_t)BATCH * DIM * NPIX * 4);   // f32: precision anchor
  bf16*  t1     = (bf16*) alloc((size_t)BATCH * 64  * NPIX * 2);
  bf16*  x_conv = (bf16*) alloc((size_t)BATCH * C2  * NPIX * 2);
  bf16*  dwbuf  = (bf16*) alloc((size_t)BATCH * C2  * NPIX * 2);
  bf16*  kbuf   = (bf16*) alloc((size_t)BATCH * GK  * NPIX * 2);
  bf16*  attn_h = (bf16*) alloc((size_t)BATCH * C2  * NPIX * 2);
  bf16*  attn   = (bf16*) alloc((size_t)BATCH * C2  * NPIX * 2);
  float* at_mean = (float*)alloc((size_t)BATCH * C2 * 4);
  float* xc_mean = (float*)alloc((size_t)BATCH * NPIX * 4);
  float* s_sig   = (float*)alloc((size_t)BATCH * NPIX * 4);
  float* c_sig   = (float*)alloc((size_t)BATCH * C2 * 4);
  bf16* cat = (bf16*)h;  // overlay: h is dead once attn_h exists

  const dim3 blk(TPB);
  const int PT = NPIX / TPB;           // 64 position-tiles
  const int ELT = BATCH * C2 * NPIX / TPB;  // 32768 blocks for per-element kernels
  const float* x2 = h + (size_t)C2 * NPIX;  // channels 128.. of h (b-stride DIM)

  // 1. h = proj_in(x)
  pw_kernel<DIM, 0, float, float><<<dim3(PT, DIM / 8, BATCH), blk, 0, stream>>>(
      x, DIM, piw, pib, h, DIM);
  // 2. t1 = relu(cb1(x1))   (x1 = h channels 0..127)
  pw_kernel<C2, 1, float, bf16><<<dim3(PT, 64 / 8, BATCH), blk, 0, stream>>>(
      h, DIM, cbw1, cbb1, t1, 64);
  // 3. x_conv = cb2(t1)
  pw_kernel<64, 0, bf16, bf16><<<dim3(PT, C2 / 8, BATCH), blk, 0, stream>>>(
      t1, 64, cbw2, cbb2, x_conv, C2);
  // 4. dwbuf = dw_h(x2)
  dwh_kernel<float><<<dim3(ELT), blk, 0, stream>>>(x2, DIM, hkdw, hkdb, dwbuf);
  // 5. kh = tanh(hk_pw(dwbuf))
  pw_kernel<C2, 2, bf16, bf16><<<dim3(PT, GK / 8, BATCH), blk, 0, stream>>>(
      dwbuf, C2, hkpw, hkpb, kbuf, GK);
  // 6. attn_h = fsa_h(x2, kh)
  fsah_kernel<float><<<dim3(ELT), blk, 0, stream>>>(x2, DIM, kbuf, attn_h);
  // 7. dwbuf = dw_v(attn_h)
  dwv_kernel<bf16><<<dim3(ELT), blk, 0, stream>>>(attn_h, C2, vkdw, vkdb, dwbuf);
  // 8. kv = tanh(vk_pw(dwbuf))
  pw_kernel<C2, 2, bf16, bf16><<<dim3(PT, GK / 8, BATCH), blk, 0, stream>>>(
      dwbuf, C2, vkpw, vkpb, kbuf, GK);
  // 9. attn = fsa_v(attn_h, kv)
  fsav_kernel<bf16><<<dim3(ELT), blk, 0, stream>>>(attn_h, C2, kbuf, attn);
  // 10-13. gating
  mean_n_kernel<<<dim3(BATCH * C2), blk, 0, stream>>>(attn, at_mean);
  xcmean_kernel<<<dim3(PT, BATCH), blk, 0, stream>>>(x_conv, xc_mean);
  ssig_kernel<<<dim3(PT, BATCH), blk, 0, stream>>>(x_conv, at_mean, s_sig);
  csig_kernel<<<dim3(BATCH * C2), blk, 0, stream>>>(attn, xc_mean, c_sig);
  // 14. cat = [s_sig*xc ; c_sig*attn]  (overlaid on h)
  concat_kernel<<<dim3(PT, DIM, BATCH), blk, 0, stream>>>(
      x_conv, attn, s_sig, c_sig, cat);
  // 15. out = proj_out(cat)
  pw_kernel<DIM, 0, bf16, float><<<dim3(PT, DIM / 8, BATCH), blk, 0, stream>>>(
      cat, DIM, pow_, pob, out, DIM);
}

// Round 2
// 486.501 us; speedup vs baseline: 1.5169x; 1.5169x over previous
//
#include <hip/hip_runtime.h>
#include <hip/hip_bf16.h>
#include <math.h>

typedef __hip_bfloat16 bf16;
typedef __attribute__((ext_vector_type(8))) short short8;
typedef __attribute__((ext_vector_type(4))) float floatx4;
#define DEV __device__ __forceinline__

constexpr int BATCH = 4;
constexpr int DIM   = 256;
constexpr int C2    = 128;
constexpr int GK    = 40;     // HEADS*KS = 8*5
constexpr int HH    = 128;
constexpr int WW    = 128;
constexpr int NPIX  = HH * WW;   // 16384
constexpr int TPB   = 256;

DEV float toF(float v) { return v; }
DEV float toF(bf16 v)  { return __bfloat162float(v); }

DEV unsigned short f2bs(float f) {
  union { bf16 h; unsigned short u; } cv;
  cv.h = __float2bfloat16(f);
  return cv.u;
}

// ==================== MFMA pointwise conv (1x1) ====================
// out[b,o,p] = act(sum_c W[o,c]*in[b,c,p] + bias[o])
// GEMM: A = W (O x C), B = in (C x 64px), D = out tile.
// Block: 256 thr = 4 waves; px strip of 64; wave w covers o in [w*WO*16, (w+1)*WO*16).
// LDS tile: 32 channels x 64 px bf16, row stride 66 shorts (33 dwords, odd) ->
//   ds_read_u16 fragments conflict-free (2-way only), ds_write_b32 staging 2-way.
// grid: (NPIX/64, BATCH)
template<int C, int O, int WO, int ACT, typename TIN, typename TOUT>
__global__ __launch_bounds__(TPB) void pw_mfma_kernel(
    const TIN* __restrict__ in, int in_cs,
    const float* __restrict__ w, const float* __restrict__ bias,
    TOUT* __restrict__ out, int out_cs) {
  constexpr int ROWS = 66;              // 64 px + 2 pad shorts
  __shared__ short smem[32 * ROWS];

  const int p0   = blockIdx.x * 64;
  const int b    = blockIdx.y;
  const int lane = threadIdx.x & 63;
  const int wid  = threadIdx.x >> 6;
  const int q    = lane >> 4;           // quad 0..3
  const int i16  = lane & 15;
  const int o_base = wid * WO * 16;
  const bool wave_active = (o_base < O);

  floatx4 acc[WO][4];
#pragma unroll
  for (int ot = 0; ot < WO; ++ot)
#pragma unroll
    for (int nt = 0; nt < 4; ++nt)
      acc[ot][nt] = (floatx4){0.f, 0.f, 0.f, 0.f};

  // staging assignment: group g (0..511): channel c=g>>4, px4 = (g&15)*4
  const int g0 = threadIdx.x;

  for (int kc = 0; kc < C / 32; ++kc) {
    const int c0 = kc * 32;
    // ---- stage 32ch x 64px into LDS as bf16 ----
#pragma unroll
    for (int r = 0; r < 2; ++r) {
      const int g  = g0 + r * TPB;
      const int c  = g >> 4;
      const int p4 = (g & 15) << 2;
      const TIN* src = in + ((size_t)(b * in_cs + c0 + c)) * NPIX + p0 + p4;
      unsigned int u0, u1;
      if constexpr (sizeof(TIN) == 4) {
        const floatx4 v = *reinterpret_cast<const floatx4*>(src);
        u0 = (unsigned int)f2bs(v.x) | ((unsigned int)f2bs(v.y) << 16);
        u1 = (unsigned int)f2bs(v.z) | ((unsigned int)f2bs(v.w) << 16);
      } else {
        const uint2 v = *reinterpret_cast<const uint2*>(src);
        u0 = v.x; u1 = v.y;
      }
      *reinterpret_cast<unsigned int*>(&smem[c * ROWS + p4])     = u0;
      *reinterpret_cast<unsigned int*>(&smem[c * ROWS + p4 + 2]) = u1;
    }
    __syncthreads();

    if (wave_active) {
      // ---- A fragments from global (L1/L2-hot weights) ----
      short8 afrag[WO];
#pragma unroll
      for (int ot = 0; ot < WO; ++ot) {
        int o = o_base + ot * 16 + i16;
        if (o >= O) o = O - 1;          // clamp; masked rows discarded at store
        const floatx4* wp = reinterpret_cast<const floatx4*>(
            w + (size_t)o * C + c0 + q * 8);
        const floatx4 w0 = wp[0];
        const floatx4 w1 = wp[1];
        short8 a;
        a[0] = (short)f2bs(w0.x); a[1] = (short)f2bs(w0.y);
        a[2] = (short)f2bs(w0.z); a[3] = (short)f2bs(w0.w);
        a[4] = (short)f2bs(w1.x); a[5] = (short)f2bs(w1.y);
        a[6] = (short)f2bs(w1.z); a[7] = (short)f2bs(w1.w);
        afrag[ot] = a;
      }
      // ---- B fragments from LDS: B[k=q*8+j][n=nt*16+i16] ----
      short8 bfrag[4];
#pragma unroll
      for (int nt = 0; nt < 4; ++nt) {
        short8 v;
#pragma unroll
        for (int j = 0; j < 8; ++j)
          v[j] = smem[(q * 8 + j) * ROWS + nt * 16 + i16];
        bfrag[nt] = v;
      }
      // ---- MFMA ----
#pragma unroll
      for (int ot = 0; ot < WO; ++ot)
#pragma unroll
        for (int nt = 0; nt < 4; ++nt)
          acc[ot][nt] = __builtin_amdgcn_mfma_f32_16x16x32_bf16(
              afrag[ot], bfrag[nt], acc[ot][nt], 0, 0, 0);
    }
    __syncthreads();
  }

  // ---- epilogue: C/D layout col=lane&15, row=q*4+reg ----
  if (!wave_active) return;
#pragma unroll
  for (int ot = 0; ot < WO; ++ot) {
#pragma unroll
    for (int reg = 0; reg < 4; ++reg) {
      const int o = o_base + ot * 16 + q * 4 + reg;
      if (o < O) {
        const float bv = bias[o];
#pragma unroll
        for (int nt = 0; nt < 4; ++nt) {
          float v = acc[ot][nt][reg] + bv;
          if (ACT == 1) v = fmaxf(v, 0.0f);
          if (ACT == 2) v = tanhf(v);
          TOUT* dst = out + ((size_t)(b * out_cs + o)) * NPIX + p0 + nt * 16 + i16;
          if constexpr (sizeof(TOUT) == 4) *dst = v;
          else *dst = __float2bfloat16(v);
        }
      }
    }
  }
}

// -------------------- depthwise 1x7 conv along W, zero pad 3
template<typename TIN>
__global__ __launch_bounds__(TPB) void dwh_kernel(
    const TIN* __restrict__ in, int in_cstride,
    const float* __restrict__ w7, const float* __restrict__ bias,
    bf16* __restrict__ out) {
  const int idx = blockIdx.x * TPB + threadIdx.x;
  const int wp  = idx & (WW - 1);
  const int rest = idx / WW;
  const int hp  = rest & (HH - 1);
  const int bc  = rest / HH;
  const int c   = bc & (C2 - 1);
  const int b   = bc / C2;
  const TIN* xr = in + ((size_t)b * in_cstride + c) * NPIX + hp * WW;
  float acc = bias[c];
#pragma unroll
  for (int j = 0; j < 7; ++j) {
    int wq = wp - 3 + j;
    if (wq >= 0 && wq < WW) acc = fmaf(w7[c * 7 + j], toF(xr[wq]), acc);
  }
  out[(size_t)bc * NPIX + hp * WW + wp] = __float2bfloat16(acc);
}

// -------------------- depthwise 7x1 conv along H, zero pad 3
template<typename TIN>
__global__ __launch_bounds__(TPB) void dwv_kernel(
    const TIN* __restrict__ in, int in_cstride,
    const float* __restrict__ w7, const float* __restrict__ bias,
    bf16* __restrict__ out) {
  const int idx = blockIdx.x * TPB + threadIdx.x;
  const int wp  = idx & (WW - 1);
  const int rest = idx / WW;
  const int hp  = rest & (HH - 1);
  const int bc  = rest / HH;
  const int c   = bc & (C2 - 1);
  const int b   = bc / C2;
  const TIN* xcol = in + ((size_t)b * in_cstride + c) * NPIX + wp;
  float acc = bias[c];
#pragma unroll
  for (int j = 0; j < 7; ++j) {
    int hq = hp - 3 + j;
    if (hq >= 0 && hq < HH) acc = fmaf(w7[c * 7 + j], toF(xcol[(size_t)hq * WW]), acc);
  }
  out[(size_t)bc * NPIX + hp * WW + wp] = __float2bfloat16(acc);
}

// -------------------- FSA horizontal
template<typename TIN>
__global__ __launch_bounds__(TPB) void fsah_kernel(
    const TIN* __restrict__ x, int x_cstride,
    const bf16* __restrict__ kern, bf16* __restrict__ out) {
  const int idx = blockIdx.x * TPB + threadIdx.x;
  const int wp  = idx & (WW - 1);
  const int rest = idx / WW;
  const int hp  = rest & (HH - 1);
  const int bc  = rest / HH;
  const int c   = bc & (C2 - 1);
  const int b   = bc / C2;
  const TIN* xr = x + ((size_t)b * x_cstride + c) * NPIX + hp * WW;
  float xs[7];
#pragma unroll
  for (int j = 0; j < 7; ++j) {
    int wq = wp - 3 + j;
    xs[j] = (wq >= 0 && wq < WW) ? toF(xr[wq]) : 0.0f;
  }
  const bf16* kr = kern + ((size_t)b * GK + (c >> 4) * 5) * NPIX + hp * WW + wp;
  float acc = 0.5f * (xs[0] + xs[1]) * toF(kr[0]);
  acc = fmaf(xs[2], toF(kr[(size_t)1 * NPIX]), acc);
  acc = fmaf(xs[3], toF(kr[(size_t)2 * NPIX]), acc);
  acc = fmaf(xs[4], toF(kr[(size_t)3 * NPIX]), acc);
  acc = fmaf(0.5f * (xs[5] + xs[6]), toF(kr[(size_t)4 * NPIX]), acc);
  out[(size_t)bc * NPIX + hp * WW + wp] = __float2bfloat16(acc);
}

// -------------------- FSA vertical
template<typename TIN>
__global__ __launch_bounds__(TPB) void fsav_kernel(
    const TIN* __restrict__ x, int x_cstride,
    const bf16* __restrict__ kern, bf16* __restrict__ out) {
  const int idx = blockIdx.x * TPB + threadIdx.x;
  const int wp  = idx & (WW - 1);
  const int rest = idx / WW;
  const int hp  = rest & (HH - 1);
  const int bc  = rest / HH;
  const int c   = bc & (C2 - 1);
  const int b   = bc / C2;
  const TIN* xcol = x + ((size_t)b * x_cstride + c) * NPIX + wp;
  float xs[7];
#pragma unroll
  for (int j = 0; j < 7; ++j) {
    int hq = hp - 3 + j;
    xs[j] = (hq >= 0 && hq < HH) ? toF(xcol[(size_t)hq * WW]) : 0.0f;
  }
  const bf16* kr = kern + ((size_t)b * GK + (c >> 4) * 5) * NPIX + hp * WW + wp;
  float acc = 0.5f * (xs[0] + xs[1]) * toF(kr[0]);
  acc = fmaf(xs[2], toF(kr[(size_t)1 * NPIX]), acc);
  acc = fmaf(xs[3], toF(kr[(size_t)2 * NPIX]), acc);
  acc = fmaf(xs[4], toF(kr[(size_t)3 * NPIX]), acc);
  acc = fmaf(0.5f * (xs[5] + xs[6]), toF(kr[(size_t)4 * NPIX]), acc);
  out[(size_t)bc * NPIX + hp * WW + wp] = __float2bfloat16(acc);
}

// -------------------- block reduction helper (result valid in thread 0)
DEV float block_reduce_sum(float v) {
#pragma unroll
  for (int off = 32; off > 0; off >>= 1) v += __shfl_down(v, off, 64);
  __shared__ float ls[TPB / 64];
  const int lane = threadIdx.x & 63;
  const int wid  = threadIdx.x >> 6;
  if (lane == 0) ls[wid] = v;
  __syncthreads();
  float s = 0.0f;
  if (threadIdx.x == 0) {
#pragma unroll
    for (int i = 0; i < TPB / 64; ++i) s += ls[i];
  }
  return s;
}

__global__ __launch_bounds__(TPB) void mean_n_kernel(const bf16* __restrict__ in,
                                                     float* __restrict__ out) {
  const int bc = blockIdx.x;
  const bf16* r = in + (size_t)bc * NPIX;
  float s = 0.0f;
  for (int i = threadIdx.x; i < NPIX; i += TPB) s += toF(r[i]);
  s = block_reduce_sum(s);
  if (threadIdx.x == 0) out[bc] = s * (1.0f / NPIX);
}

__global__ __launch_bounds__(TPB) void xcmean_kernel(const bf16* __restrict__ xc,
                                                     float* __restrict__ out) {
  const int p = blockIdx.x * TPB + threadIdx.x;
  const int b = blockIdx.y;
  const bf16* r = xc + (size_t)b * C2 * NPIX + p;
  float s = 0.0f;
#pragma unroll 4
  for (int c = 0; c < C2; ++c) s += toF(r[(size_t)c * NPIX]);
  out[(size_t)b * NPIX + p] = s * (1.0f / C2);
}

__global__ __launch_bounds__(TPB) void ssig_kernel(const bf16* __restrict__ xc,
                                                   const float* __restrict__ at_mean,
                                                   float* __restrict__ out) {
  __shared__ float am[C2];
  const int b = blockIdx.y;
  if (threadIdx.x < C2) am[threadIdx.x] = at_mean[b * C2 + threadIdx.x];
  __syncthreads();
  const int p = blockIdx.x * TPB + threadIdx.x;
  const bf16* r = xc + (size_t)b * C2 * NPIX + p;
  float s = 0.0f;
#pragma unroll 4
  for (int c = 0; c < C2; ++c) s = fmaf(am[c], toF(r[(size_t)c * NPIX]), s);
  out[(size_t)b * NPIX + p] = 1.0f / (1.0f + expf(-s * (1.0f / C2)));
}

__global__ __launch_bounds__(TPB) void csig_kernel(const bf16* __restrict__ attn,
                                                   const float* __restrict__ xc_mean,
                                                   float* __restrict__ out) {
  const int bc = blockIdx.x;
  const int b  = bc / C2;
  const bf16* r = attn + (size_t)bc * NPIX;
  const float* m = xc_mean + (size_t)b * NPIX;
  float s = 0.0f;
  for (int i = threadIdx.x; i < NPIX; i += TPB) s = fmaf(toF(r[i]), m[i], s);
  s = block_reduce_sum(s);
  if (threadIdx.x == 0) out[bc] = 1.0f / (1.0f + expf(-s * (1.0f / NPIX)));
}

__global__ __launch_bounds__(TPB) void concat_kernel(const bf16* __restrict__ xc,
                                                     const bf16* __restrict__ attn,
                                                     const float* __restrict__ s_sig,
                                                     const float* __restrict__ c_sig,
                                                     bf16* __restrict__ out) {
  const int p = blockIdx.x * TPB + threadIdx.x;
  const int c = blockIdx.y;
  const int b = blockIdx.z;
  float v;
  if (c < C2) {
    v = s_sig[(size_t)b * NPIX + p] * toF(xc[((size_t)b * C2 + c) * NPIX + p]);
  } else {
    v = c_sig[b * C2 + (c - C2)] * toF(attn[((size_t)b * C2 + (c - C2)) * NPIX + p]);
  }
  out[((size_t)b * DIM + c) * NPIX + p] = __float2bfloat16(v);
}

extern "C" void kernel_launch(void* const* d_in, const int* in_sizes, int n_in,
                              void* d_out, int out_size, void* d_ws, size_t ws_size,
                              hipStream_t stream) {
  const float* x    = (const float*)d_in[0];
  const float* piw  = (const float*)d_in[1];
  const float* pib  = (const float*)d_in[2];
  const float* hkdw = (const float*)d_in[3];
  const float* hkdb = (const float*)d_in[4];
  const float* hkpw = (const float*)d_in[5];
  const float* hkpb = (const float*)d_in[6];
  const float* vkdw = (const float*)d_in[7];
  const float* vkdb = (const float*)d_in[8];
  const float* vkpw = (const float*)d_in[9];
  const float* vkpb = (const float*)d_in[10];
  const float* cbw1 = (const float*)d_in[11];
  const float* cbb1 = (const float*)d_in[12];
  const float* cbw2 = (const float*)d_in[13];
  const float* cbb2 = (const float*)d_in[14];
  const float* pow_ = (const float*)d_in[15];
  const float* pob  = (const float*)d_in[16];
  float* out = (float*)d_out;

  char* ws = (char*)d_ws;
  size_t off = 0;
  auto alloc = [&](size_t bytes) -> char* {
    char* p = ws + off;
    off += (bytes + 255) & ~(size_t)255;
    return p;
  };
  float* h      = (float*)alloc((size_t)BATCH * DIM * NPIX * 4);   // f32 precision anchor
  bf16*  t1     = (bf16*) alloc((size_t)BATCH * 64  * NPIX * 2);
  bf16*  x_conv = (bf16*) alloc((size_t)BATCH * C2  * NPIX * 2);
  bf16*  dwbuf  = (bf16*) alloc((size_t)BATCH * C2  * NPIX * 2);
  bf16*  kbuf   = (bf16*) alloc((size_t)BATCH * GK  * NPIX * 2);
  bf16*  attn_h = (bf16*) alloc((size_t)BATCH * C2  * NPIX * 2);
  bf16*  attn   = (bf16*) alloc((size_t)BATCH * C2  * NPIX * 2);
  float* at_mean = (float*)alloc((size_t)BATCH * C2 * 4);
  float* xc_mean = (float*)alloc((size_t)BATCH * NPIX * 4);
  float* s_sig   = (float*)alloc((size_t)BATCH * NPIX * 4);
  float* c_sig   = (float*)alloc((size_t)BATCH * C2 * 4);
  bf16* cat = (bf16*)h;  // overlay: h is dead once attn_h exists

  const dim3 blk(TPB);
  const dim3 gemm_grid(NPIX / 64, BATCH);
  const int PT = NPIX / TPB;                 // 64 position-tiles
  const int ELT = BATCH * C2 * NPIX / TPB;   // per-element kernel blocks
  const float* x2 = h + (size_t)C2 * NPIX;   // channels 128.. of h (b-stride DIM)

  // 1. h = proj_in(x)           MFMA GEMM K=256, O=256
  pw_mfma_kernel<DIM, DIM, 4, 0, float, float><<<gemm_grid, blk, 0, stream>>>(
      x, DIM, piw, pib, h, DIM);
  // 2. t1 = relu(cb1(x1))       K=128, O=64
  pw_mfma_kernel<C2, 64, 1, 1, float, bf16><<<gemm_grid, blk, 0, stream>>>(
      h, DIM, cbw1, cbb1, t1, 64);
  // 3. x_conv = cb2(t1)         K=64, O=128
  pw_mfma_kernel<64, C2, 2, 0, bf16, bf16><<<gemm_grid, blk, 0, stream>>>(
      t1, 64, cbw2, cbb2, x_conv, C2);
  // 4. dwbuf = dw_h(x2)
  dwh_kernel<float><<<dim3(ELT), blk, 0, stream>>>(x2, DIM, hkdw, hkdb, dwbuf);
  // 5. kh = tanh(hk_pw(dwbuf))  K=128, O=40
  pw_mfma_kernel<C2, GK, 1, 2, bf16, bf16><<<gemm_grid, blk, 0, stream>>>(
      dwbuf, C2, hkpw, hkpb, kbuf, GK);
  // 6. attn_h = fsa_h(x2, kh)
  fsah_kernel<float><<<dim3(ELT), blk, 0, stream>>>(x2, DIM, kbuf, attn_h);
  // 7. dwbuf = dw_v(attn_h)
  dwv_kernel<bf16><<<dim3(ELT), blk, 0, stream>>>(attn_h, C2, vkdw, vkdb, dwbuf);
  // 8. kv = tanh(vk_pw(dwbuf))  K=128, O=40
  pw_mfma_kernel<C2, GK, 1, 2, bf16, bf16><<<gemm_grid, blk, 0, stream>>>(
      dwbuf, C2, vkpw, vkpb, kbuf, GK);
  // 9. attn = fsa_v(attn_h, kv)
  fsav_kernel<bf16><<<dim3(ELT), blk, 0, stream>>>(attn_h, C2, kbuf, attn);
  // 10-13. gating
  mean_n_kernel<<<dim3(BATCH * C2), blk, 0, stream>>>(attn, at_mean);
  xcmean_kernel<<<dim3(PT, BATCH), blk, 0, stream>>>(x_conv, xc_mean);
  ssig_kernel<<<dim3(PT, BATCH), blk, 0, stream>>>(x_conv, at_mean, s_sig);
  csig_kernel<<<dim3(BATCH * C2), blk, 0, stream>>>(attn, xc_mean, c_sig);
  // 14. cat = [s_sig*xc ; c_sig*attn]  (overlaid on h)
  concat_kernel<<<dim3(PT, DIM, BATCH), blk, 0, stream>>>(
      x_conv, attn, s_sig, c_sig, cat);
  // 15. out = proj_out(cat)     MFMA GEMM K=256, O=256
  pw_mfma_kernel<DIM, DIM, 4, 0, bf16, float><<<gemm_grid, blk, 0, stream>>>(
      cat, DIM, pow_, pob, out, DIM);
}

// Round 3
// 304.101 us; speedup vs baseline: 2.4267x; 1.5998x over previous
//
#include <hip/hip_runtime.h>
#include <hip/hip_bf16.h>
#include <math.h>

typedef __hip_bfloat16 bf16;
typedef __attribute__((ext_vector_type(8))) short short8;
typedef __attribute__((ext_vector_type(4))) float floatx4;
#define DEV __device__ __forceinline__

constexpr int BATCH = 4;
constexpr int DIM   = 256;
constexpr int C2    = 128;
constexpr int GK    = 40;     // HEADS*KS = 8*5
constexpr int HH    = 128;
constexpr int WW    = 128;
constexpr int NPIX  = HH * WW;   // 16384
constexpr int TPB   = 256;

DEV float toF(float v) { return v; }
DEV float toF(bf16 v)  { return __bfloat162float(v); }

DEV unsigned short f2bs(float f) {
  union { bf16 h; unsigned short u; } cv;
  cv.h = __float2bfloat16(f);
  return cv.u;
}
DEV float bs2f(unsigned short u) {
  union { float f; unsigned x; } c;
  c.x = ((unsigned)u) << 16;
  return c.f;
}

// load N f32 / bf16 values into float array (explicit vector widths)
template<int N>
DEV void load_f32v(const float* __restrict__ p, float* v) {
  if constexpr (N == 8) {
    const float4 a = *(const float4*)p;
    const float4 b = *(const float4*)(p + 4);
    v[0]=a.x; v[1]=a.y; v[2]=a.z; v[3]=a.w; v[4]=b.x; v[5]=b.y; v[6]=b.z; v[7]=b.w;
  } else if constexpr (N == 4) {
    const float4 a = *(const float4*)p;
    v[0]=a.x; v[1]=a.y; v[2]=a.z; v[3]=a.w;
  } else {
    const float2 a = *(const float2*)p;
    v[0]=a.x; v[1]=a.y;
  }
}
template<int N>
DEV void load_bf16v(const bf16* __restrict__ p, float* v) {
  if constexpr (N == 8) {
    const uint4 u = *(const uint4*)p;
    v[0]=bs2f(u.x & 0xffff); v[1]=bs2f(u.x >> 16);
    v[2]=bs2f(u.y & 0xffff); v[3]=bs2f(u.y >> 16);
    v[4]=bs2f(u.z & 0xffff); v[5]=bs2f(u.z >> 16);
    v[6]=bs2f(u.w & 0xffff); v[7]=bs2f(u.w >> 16);
  } else if constexpr (N == 4) {
    const uint2 u = *(const uint2*)p;
    v[0]=bs2f(u.x & 0xffff); v[1]=bs2f(u.x >> 16);
    v[2]=bs2f(u.y & 0xffff); v[3]=bs2f(u.y >> 16);
  } else {
    const unsigned u = *(const unsigned*)p;
    v[0]=bs2f(u & 0xffff); v[1]=bs2f(u >> 16);
  }
}
DEV void load8bf(const bf16* __restrict__ p, float* v) { load_bf16v<8>(p, v); }

// ==================== weight prepack: f32 -> bf16, 6 matrices concatenated ====
// dst layout: [proj_in 65536][cb1 8192][cb2 8192][hk_pw 5120][vk_pw 5120][proj_out 65536]
__global__ __launch_bounds__(TPB) void prepack_kernel(
    const float* __restrict__ w0, const float* __restrict__ w1,
    const float* __restrict__ w2, const float* __restrict__ w3,
    const float* __restrict__ w4, const float* __restrict__ w5,
    short* __restrict__ dst) {
  const int i = blockIdx.x * TPB + threadIdx.x;
  if (i >= 157696) return;
  int j = i;
  float v;
  if (j < 65536) v = w0[j];
  else if ((j -= 65536) < 8192) v = w1[j];
  else if ((j -= 8192) < 8192) v = w2[j];
  else if ((j -= 8192) < 5120) v = w3[j];
  else if ((j -= 5120) < 5120) v = w4[j];
  else { j -= 5120; v = w5[j]; }
  dst[i] = (short)f2bs(v);
}

// ==================== MFMA pointwise conv v2 ====================
// out[b,o,p] = act(sum_c W[o,c]*in[b,c,p] + bias[o])
// Full-K LDS staging: tile[n=64 px][k=K] bf16, 16B-octet XOR swizzle
// (phys_oct = oct ^ ((n>>3)&7)); row stride K*2+16 bytes (dwords ≡ 4 mod 32)
// -> ds_write_b128 staging and ds_read_b128 fragments, both 2-way (free).
// Weights prepacked bf16 [O][K]: A-fragment = one 16B global load (L2-hot).
// GATED: input = [s_sig*xc ; c_sig*attn] (fused concat for proj_out).
// grid: (NPIX/64, BATCH), block 256 = 4 waves; wave covers WO*16 output chans.
template<int K, int O, int ACT, int GATED, typename TIN, typename TOUT>
__global__ __launch_bounds__(TPB) void pw2_kernel(
    const TIN* __restrict__ in, int in_bs,
    const short* __restrict__ wbf, const float* __restrict__ bias,
    TOUT* __restrict__ out, int out_bs,
    const bf16* __restrict__ gxc, const bf16* __restrict__ gattn,
    const float* __restrict__ gs, const float* __restrict__ gc) {
  constexpr int C8   = K / 8;        // channel octets
  constexpr int PXT  = K / 32;       // px per staging thread (8/4/2)
  constexpr int PG   = 64 / PXT;     // px groups per channel octet
  constexpr int ROWB = K * 2 + 16;   // LDS row bytes (16B pad keeps rowD%32==4)
  constexpr int WO   = (O + 63) / 64;
  __shared__ char smem[64 * ROWB];

  const int p0   = blockIdx.x * 64;
  const int b    = blockIdx.y;
  const int t    = threadIdx.x;
  const int lane = t & 63, wid = t >> 6;
  const int q    = lane >> 4, i16 = lane & 15;

  // ---------- stage 64px x K tile ----------
  {
    const int c8  = t / PG;          // 0..C8-1
    const int px0 = (t % PG) * PXT;
    float vals[8][PXT];
    float svals[PXT];
    if constexpr (GATED) {
      if (c8 < C8 / 2) load_f32v<PXT>(gs + (size_t)b * NPIX + p0 + px0, svals);
    }
#pragma unroll
    for (int j = 0; j < 8; ++j) {
      const int c = c8 * 8 + j;
      float tmp[PXT];
      if constexpr (GATED) {
        if (c < C2) {
          load_bf16v<PXT>(gxc + ((size_t)b * C2 + c) * NPIX + p0 + px0, tmp);
#pragma unroll
          for (int px = 0; px < PXT; ++px) vals[j][px] = tmp[px] * svals[px];
        } else {
          const float cg = gc[b * C2 + (c - C2)];
          load_bf16v<PXT>(gattn + ((size_t)b * C2 + (c - C2)) * NPIX + p0 + px0, tmp);
#pragma unroll
          for (int px = 0; px < PXT; ++px) vals[j][px] = tmp[px] * cg;
        }
      } else {
        const TIN* src = in + ((size_t)b * in_bs + c) * NPIX + p0 + px0;
        if constexpr (sizeof(TIN) == 4) load_f32v<PXT>((const float*)src, tmp);
        else                            load_bf16v<PXT>((const bf16*)src, tmp);
#pragma unroll
        for (int px = 0; px < PXT; ++px) vals[j][px] = tmp[px];
      }
    }
#pragma unroll
    for (int px = 0; px < PXT; ++px) {
      const int p = px0 + px;
      short8 pk;
#pragma unroll
      for (int j = 0; j < 8; ++j) pk[j] = (short)f2bs(vals[j][px]);
      const int phys = c8 ^ ((p >> 3) & 7);
      *reinterpret_cast<short8*>(smem + (size_t)p * ROWB + phys * 16) = pk;
    }
  }
  __syncthreads();

  const int o_base = wid * WO * 16;
  if (o_base >= O) return;

  floatx4 acc[WO][4];
#pragma unroll
  for (int ot = 0; ot < WO; ++ot)
#pragma unroll
    for (int nt = 0; nt < 4; ++nt)
      acc[ot][nt] = (floatx4){0.f, 0.f, 0.f, 0.f};

  for (int kc = 0; kc < K / 32; ++kc) {
    short8 afrag[WO];
#pragma unroll
    for (int ot = 0; ot < WO; ++ot) {
      int o = o_base + ot * 16 + i16;
      if (o >= O) o = O - 1;          // clamp; masked at store
      afrag[ot] = *reinterpret_cast<const short8*>(wbf + (size_t)o * K + kc * 32 + q * 8);
    }
    short8 bfrag[4];
#pragma unroll
    for (int nt = 0; nt < 4; ++nt) {
      const int n = nt * 16 + i16;
      const int phys = (kc * 4 + q) ^ ((n >> 3) & 7);
      bfrag[nt] = *reinterpret_cast<const short8*>(smem + (size_t)n * ROWB + phys * 16);
    }
#pragma unroll
    for (int ot = 0; ot < WO; ++ot)
#pragma unroll
      for (int nt = 0; nt < 4; ++nt)
        acc[ot][nt] = __builtin_amdgcn_mfma_f32_16x16x32_bf16(
            afrag[ot], bfrag[nt], acc[ot][nt], 0, 0, 0);
  }

  // epilogue: C/D layout col=lane&15, row=q*4+reg  (validated R2)
#pragma unroll
  for (int ot = 0; ot < WO; ++ot) {
#pragma unroll
    for (int reg = 0; reg < 4; ++reg) {
      const int o = o_base + ot * 16 + q * 4 + reg;
      if (o < O) {
        const float bv = bias[o];
#pragma unroll
        for (int nt = 0; nt < 4; ++nt) {
          float v = acc[ot][nt][reg] + bv;
          if (ACT == 1) v = fmaxf(v, 0.0f);
          if (ACT == 2) v = tanhf(v);
          TOUT* dst = out + ((size_t)b * out_bs + o) * NPIX + p0 + nt * 16 + i16;
          if constexpr (sizeof(TOUT) == 4) *dst = v;
          else *dst = __float2bfloat16(v);
        }
      }
    }
  }
}

// ==================== depthwise 1x7 along W (f32 in), 8 px/thread ============
__global__ __launch_bounds__(TPB) void dwh2_kernel(
    const float* __restrict__ in, int in_bs,
    const float* __restrict__ w7, const float* __restrict__ bias,
    bf16* __restrict__ out) {
  const int g  = blockIdx.x * TPB + threadIdx.x;
  const int w8 = g & 15;
  const int hp = (g >> 4) & (HH - 1);
  const int c  = (g >> 11) & (C2 - 1);
  const int b  = g >> 18;
  const float* xr = in + ((size_t)b * in_bs + c) * NPIX + hp * WW;
  const int px0 = w8 * 8;
  float xs[14];                       // window px0-3 .. px0+10
  if (w8 > 0) { const float4 L = *(const float4*)(xr + px0 - 4); xs[0]=L.y; xs[1]=L.z; xs[2]=L.w; }
  else { xs[0]=xs[1]=xs[2]=0.f; }
  { const float4 a = *(const float4*)(xr + px0);
    const float4 bq = *(const float4*)(xr + px0 + 4);
    xs[3]=a.x; xs[4]=a.y; xs[5]=a.z; xs[6]=a.w;
    xs[7]=bq.x; xs[8]=bq.y; xs[9]=bq.z; xs[10]=bq.w; }
  if (w8 < 15) { const float4 R = *(const float4*)(xr + px0 + 8); xs[11]=R.x; xs[12]=R.y; xs[13]=R.z; }
  else { xs[11]=xs[12]=xs[13]=0.f; }
  float wv[7];
#pragma unroll
  for (int j = 0; j < 7; ++j) wv[j] = w7[c * 7 + j];
  const float bv = bias[c];
  short8 o;
#pragma unroll
  for (int i = 0; i < 8; ++i) {
    float a = bv;
#pragma unroll
    for (int j = 0; j < 7; ++j) a = fmaf(wv[j], xs[i + j], a);
    o[i] = (short)f2bs(a);
  }
  *reinterpret_cast<short8*>(out + ((size_t)(b * C2 + c)) * NPIX + hp * WW + px0) = o;
}

// ==================== depthwise 7x1 along H (bf16 in), 8 px/thread ===========
__global__ __launch_bounds__(TPB) void dwv2_kernel(
    const bf16* __restrict__ in,
    const float* __restrict__ w7, const float* __restrict__ bias,
    bf16* __restrict__ out) {
  const int g  = blockIdx.x * TPB + threadIdx.x;
  const int w8 = g & 15;
  const int hp = (g >> 4) & (HH - 1);
  const int c  = (g >> 11) & (C2 - 1);
  const int b  = g >> 18;
  const int px0 = w8 * 8;
  const bf16* base = in + ((size_t)(b * C2 + c)) * NPIX + px0;
  float r[7][8];
#pragma unroll
  for (int j = 0; j < 7; ++j) {
    const int hq = hp - 3 + j;
    if (hq >= 0 && hq < HH) load8bf(base + (size_t)hq * WW, r[j]);
    else
#pragma unroll
      for (int i = 0; i < 8; ++i) r[j][i] = 0.f;
  }
  float wv[7];
#pragma unroll
  for (int j = 0; j < 7; ++j) wv[j] = w7[c * 7 + j];
  const float bv = bias[c];
  short8 o;
#pragma unroll
  for (int i = 0; i < 8; ++i) {
    float a = bv;
#pragma unroll
    for (int j = 0; j < 7; ++j) a = fmaf(wv[j], r[j][i], a);
    o[i] = (short)f2bs(a);
  }
  *reinterpret_cast<short8*>(out + ((size_t)(b * C2 + c)) * NPIX + hp * WW + px0) = o;
}

// ==================== FSA horizontal (f32 x2, bf16 kern), 8 px/thread ========
__global__ __launch_bounds__(TPB) void fsah2_kernel(
    const float* __restrict__ x, int x_bs,
    const bf16* __restrict__ kern, bf16* __restrict__ out) {
  const int g  = blockIdx.x * TPB + threadIdx.x;
  const int w8 = g & 15;
  const int hp = (g >> 4) & (HH - 1);
  const int c  = (g >> 11) & (C2 - 1);
  const int b  = g >> 18;
  const float* xr = x + ((size_t)b * x_bs + c) * NPIX + hp * WW;
  const int px0 = w8 * 8;
  float xs[14];
  if (w8 > 0) { const float4 L = *(const float4*)(xr + px0 - 4); xs[0]=L.y; xs[1]=L.z; xs[2]=L.w; }
  else { xs[0]=xs[1]=xs[2]=0.f; }
  { const float4 a = *(const float4*)(xr + px0);
    const float4 bq = *(const float4*)(xr + px0 + 4);
    xs[3]=a.x; xs[4]=a.y; xs[5]=a.z; xs[6]=a.w;
    xs[7]=bq.x; xs[8]=bq.y; xs[9]=bq.z; xs[10]=bq.w; }
  if (w8 < 15) { const float4 R = *(const float4*)(xr + px0 + 8); xs[11]=R.x; xs[12]=R.y; xs[13]=R.z; }
  else { xs[11]=xs[12]=xs[13]=0.f; }
  float k[5][8];
  const bf16* kr = kern + ((size_t)b * GK + (c >> 4) * 5) * NPIX + hp * WW + px0;
#pragma unroll
  for (int tp = 0; tp < 5; ++tp) load8bf(kr + (size_t)tp * NPIX, k[tp]);
  short8 o;
#pragma unroll
  for (int i = 0; i < 8; ++i) {
    float a = 0.5f * (xs[i] + xs[i + 1]) * k[0][i];
    a = fmaf(xs[i + 2], k[1][i], a);
    a = fmaf(xs[i + 3], k[2][i], a);
    a = fmaf(xs[i + 4], k[3][i], a);
    a = fmaf(0.5f * (xs[i + 5] + xs[i + 6]), k[4][i], a);
    o[i] = (short)f2bs(a);
  }
  *reinterpret_cast<short8*>(out + ((size_t)(b * C2 + c)) * NPIX + hp * WW + px0) = o;
}

// ==================== FSA vertical (bf16 in + kern), 8 px/thread =============
__global__ __launch_bounds__(TPB) void fsav2_kernel(
    const bf16* __restrict__ x,
    const bf16* __restrict__ kern, bf16* __restrict__ out) {
  const int g  = blockIdx.x * TPB + threadIdx.x;
  const int w8 = g & 15;
  const int hp = (g >> 4) & (HH - 1);
  const int c  = (g >> 11) & (C2 - 1);
  const int b  = g >> 18;
  const int px0 = w8 * 8;
  const bf16* base = x + ((size_t)(b * C2 + c)) * NPIX + px0;
  float r[7][8];
#pragma unroll
  for (int j = 0; j < 7; ++j) {
    const int hq = hp - 3 + j;
    if (hq >= 0 && hq < HH) load8bf(base + (size_t)hq * WW, r[j]);
    else
#pragma unroll
      for (int i = 0; i < 8; ++i) r[j][i] = 0.f;
  }
  float k[5][8];
  const bf16* kr = kern + ((size_t)b * GK + (c >> 4) * 5) * NPIX + hp * WW + px0;
#pragma unroll
  for (int tp = 0; tp < 5; ++tp) load8bf(kr + (size_t)tp * NPIX, k[tp]);
  short8 o;
#pragma unroll
  for (int i = 0; i < 8; ++i) {
    float a = 0.5f * (r[0][i] + r[1][i]) * k[0][i];
    a = fmaf(r[2][i], k[1][i], a);
    a = fmaf(r[3][i], k[2][i], a);
    a = fmaf(r[4][i], k[3][i], a);
    a = fmaf(0.5f * (r[5][i] + r[6][i]), k[4][i], a);
    o[i] = (short)f2bs(a);
  }
  *reinterpret_cast<short8*>(out + ((size_t)(b * C2 + c)) * NPIX + hp * WW + px0) = o;
}

// -------------------- block reduction (result valid in thread 0)
DEV float block_reduce_sum(float v) {
#pragma unroll
  for (int off = 32; off > 0; off >>= 1) v += __shfl_down(v, off, 64);
  __shared__ float ls[TPB / 64];
  const int lane = threadIdx.x & 63;
  const int wid  = threadIdx.x >> 6;
  if (lane == 0) ls[wid] = v;
  __syncthreads();
  float s = 0.0f;
  if (threadIdx.x == 0) {
#pragma unroll
    for (int i = 0; i < TPB / 64; ++i) s += ls[i];
  }
  return s;
}

__global__ __launch_bounds__(TPB) void mean_n_kernel(const bf16* __restrict__ in,
                                                     float* __restrict__ out) {
  const int bc = blockIdx.x;
  const bf16* r = in + (size_t)bc * NPIX;
  float s = 0.0f;
  for (int i = threadIdx.x * 8; i < NPIX; i += TPB * 8) {
    float v[8];
    load8bf(r + i, v);
#pragma unroll
    for (int j = 0; j < 8; ++j) s += v[j];
  }
  s = block_reduce_sum(s);
  if (threadIdx.x == 0) out[bc] = s * (1.0f / NPIX);
}

__global__ __launch_bounds__(TPB) void xcmean_kernel(const bf16* __restrict__ xc,
                                                     float* __restrict__ out) {
  const int p = blockIdx.x * TPB + threadIdx.x;
  const int b = blockIdx.y;
  const bf16* r = xc + (size_t)b * C2 * NPIX + p;
  float s = 0.0f;
#pragma unroll 4
  for (int c = 0; c < C2; ++c) s += toF(r[(size_t)c * NPIX]);
  out[(size_t)b * NPIX + p] = s * (1.0f / C2);
}

__global__ __launch_bounds__(TPB) void ssig_kernel(const bf16* __restrict__ xc,
                                                   const float* __restrict__ at_mean,
                                                   float* __restrict__ out) {
  __shared__ float am[C2];
  const int b = blockIdx.y;
  if (threadIdx.x < C2) am[threadIdx.x] = at_mean[b * C2 + threadIdx.x];
  __syncthreads();
  const int p = blockIdx.x * TPB + threadIdx.x;
  const bf16* r = xc + (size_t)b * C2 * NPIX + p;
  float s = 0.0f;
#pragma unroll 4
  for (int c = 0; c < C2; ++c) s = fmaf(am[c], toF(r[(size_t)c * NPIX]), s);
  out[(size_t)b * NPIX + p] = 1.0f / (1.0f + expf(-s * (1.0f / C2)));
}

__global__ __launch_bounds__(TPB) void csig_kernel(const bf16* __restrict__ attn,
                                                   const float* __restrict__ xc_mean,
                                                   float* __restrict__ out) {
  const int bc = blockIdx.x;
  const int b  = bc / C2;
  const bf16* r = attn + (size_t)bc * NPIX;
  const float* m = xc_mean + (size_t)b * NPIX;
  float s = 0.0f;
  for (int i = threadIdx.x * 8; i < NPIX; i += TPB * 8) {
    float v[8], mm[8];
    load8bf(r + i, v);
    load_f32v<8>(m + i, mm);
#pragma unroll
    for (int j = 0; j < 8; ++j) s = fmaf(v[j], mm[j], s);
  }
  s = block_reduce_sum(s);
  if (threadIdx.x == 0) out[bc] = 1.0f / (1.0f + expf(-s * (1.0f / NPIX)));
}

extern "C" void kernel_launch(void* const* d_in, const int* in_sizes, int n_in,
                              void* d_out, int out_size, void* d_ws, size_t ws_size,
                              hipStream_t stream) {
  const float* x    = (const float*)d_in[0];
  const float* piw  = (const float*)d_in[1];
  const float* pib  = (const float*)d_in[2];
  const float* hkdw = (const float*)d_in[3];
  const float* hkdb = (const float*)d_in[4];
  const float* hkpw = (const float*)d_in[5];
  const float* hkpb = (const float*)d_in[6];
  const float* vkdw = (const float*)d_in[7];
  const float* vkdb = (const float*)d_in[8];
  const float* vkpw = (const float*)d_in[9];
  const float* vkpb = (const float*)d_in[10];
  const float* cbw1 = (const float*)d_in[11];
  const float* cbb1 = (const float*)d_in[12];
  const float* cbw2 = (const float*)d_in[13];
  const float* cbb2 = (const float*)d_in[14];
  const float* pow_ = (const float*)d_in[15];
  const float* pob  = (const float*)d_in[16];
  float* out = (float*)d_out;

  char* ws = (char*)d_ws;
  size_t off = 0;
  auto alloc = [&](size_t bytes) -> char* {
    char* p = ws + off;
    off += (bytes + 255) & ~(size_t)255;
    return p;
  };
  short* wpk    = (short*)alloc(157696 * 2);                       // packed bf16 weights
  float* h      = (float*)alloc((size_t)BATCH * DIM * NPIX * 4);   // f32 precision anchor
  bf16*  t1     = (bf16*) alloc((size_t)BATCH * 64  * NPIX * 2);
  bf16*  x_conv = (bf16*) alloc((size_t)BATCH * C2  * NPIX * 2);
  bf16*  dwbuf  = (bf16*) alloc((size_t)BATCH * C2  * NPIX * 2);
  bf16*  kbuf   = (bf16*) alloc((size_t)BATCH * GK  * NPIX * 2);
  bf16*  attn_h = (bf16*) alloc((size_t)BATCH * C2  * NPIX * 2);
  bf16*  attn   = (bf16*) alloc((size_t)BATCH * C2  * NPIX * 2);
  float* at_mean = (float*)alloc((size_t)BATCH * C2 * 4);
  float* xc_mean = (float*)alloc((size_t)BATCH * NPIX * 4);
  float* s_sig   = (float*)alloc((size_t)BATCH * NPIX * 4);
  float* c_sig   = (float*)alloc((size_t)BATCH * C2 * 4);

  const short* w_pi  = wpk;
  const short* w_cb1 = wpk + 65536;
  const short* w_cb2 = wpk + 73728;
  const short* w_hk  = wpk + 81920;
  const short* w_vk  = wpk + 87040;
  const short* w_po  = wpk + 92160;

  const dim3 blk(TPB);
  const dim3 gemm_grid(NPIX / 64, BATCH);
  const int PT  = NPIX / TPB;
  const int EL8 = BATCH * C2 * HH * 16 / TPB;   // 8px/thread elementwise blocks
  const float* x2 = h + (size_t)C2 * NPIX;      // channels 128.. of h (batch stride DIM)

  // 0. prepack weights -> bf16
  prepack_kernel<<<dim3((157696 + TPB - 1) / TPB), blk, 0, stream>>>(
      piw, cbw1, cbw2, hkpw, vkpw, pow_, wpk);
  // 1. h = proj_in(x)            K=256 O=256
  pw2_kernel<256, 256, 0, 0, float, float><<<gemm_grid, blk, 0, stream>>>(
      x, DIM, w_pi, pib, h, DIM, nullptr, nullptr, nullptr, nullptr);
  // 2. t1 = relu(cb1(x1))        K=128 O=64
  pw2_kernel<128, 64, 1, 0, float, bf16><<<gemm_grid, blk, 0, stream>>>(
      h, DIM, w_cb1, cbb1, t1, 64, nullptr, nullptr, nullptr, nullptr);
  // 3. x_conv = cb2(t1)          K=64 O=128
  pw2_kernel<64, 128, 0, 0, bf16, bf16><<<gemm_grid, blk, 0, stream>>>(
      t1, 64, w_cb2, cbb2, x_conv, C2, nullptr, nullptr, nullptr, nullptr);
  // 4. dwbuf = dw_h(x2)
  dwh2_kernel<<<dim3(EL8), blk, 0, stream>>>(x2, DIM, hkdw, hkdb, dwbuf);
  // 5. kh = tanh(hk_pw(dwbuf))   K=128 O=40
  pw2_kernel<128, 40, 2, 0, bf16, bf16><<<gemm_grid, blk, 0, stream>>>(
      dwbuf, C2, w_hk, hkpb, kbuf, GK, nullptr, nullptr, nullptr, nullptr);
  // 6. attn_h = fsa_h(x2, kh)
  fsah2_kernel<<<dim3(EL8), blk, 0, stream>>>(x2, DIM, kbuf, attn_h);
  // 7. dwbuf = dw_v(attn_h)
  dwv2_kernel<<<dim3(EL8), blk, 0, stream>>>(attn_h, vkdw, vkdb, dwbuf);
  // 8. kv = tanh(vk_pw(dwbuf))   K=128 O=40
  pw2_kernel<128, 40, 2, 0, bf16, bf16><<<gemm_grid, blk, 0, stream>>>(
      dwbuf, C2, w_vk, vkpb, kbuf, GK, nullptr, nullptr, nullptr, nullptr);
  // 9. attn = fsa_v(attn_h, kv)
  fsav2_kernel<<<dim3(EL8), blk, 0, stream>>>(attn_h, kbuf, attn);
  // 10-13. gating
  mean_n_kernel<<<dim3(BATCH * C2), blk, 0, stream>>>(attn, at_mean);
  xcmean_kernel<<<dim3(PT, BATCH), blk, 0, stream>>>(x_conv, xc_mean);
  ssig_kernel<<<dim3(PT, BATCH), blk, 0, stream>>>(x_conv, at_mean, s_sig);
  csig_kernel<<<dim3(BATCH * C2), blk, 0, stream>>>(attn, xc_mean, c_sig);
  // 14. out = proj_out([s_sig*xc ; c_sig*attn])  — concat fused into staging
  pw2_kernel<256, 256, 0, 1, bf16, float><<<gemm_grid, blk, 0, stream>>>(
      x_conv, 0, w_po, pob, out, DIM, x_conv, attn, s_sig, c_sig);
}